// Round 3
// baseline (2887.948 us; speedup 1.0000x reference)
//
#include <hip/hip_runtime.h>

#define NE 400
#define NIN 784
#define BB 512
#define TT 50

#define KC1 7          // gemm1 K-chunks over input dim (784 = 7*112)
#define KCH1 112
#define KC2 4          // gemm2 K-chunks over batch (512 = 4*128)
#define KCH2 128

constexpr float C_KE     = (float)(0.5 / 100.0);
constexpr float C_KI     = (float)(0.5 / 10.0);
constexpr float C_GSE    = 0.5f;
constexpr float C_GSI    = 0.25f;
constexpr float C_DECTH  = (float)(1.0 - 0.5 / 1e7);
constexpr float C_DEC1   = (float)(1.0 - 0.5 / 20.0);
constexpr float C_DEC2   = (float)(1.0 - 0.5 / 40.0);
constexpr float C_DECPRE = (float)(1.0 - 0.5 / 20.0);
constexpr float C_NUPRE  = (float)0.0001;
constexpr float C_NUPOST = 0.01f;

__global__ void k_init(float* g_ine, float* g_ei, float* g_ie, float* Iie,
                       float* mem_e, float* rc_e, float* mem_i, float* rc_i,
                       float* theta, float* tp1, float* tp2) {
    int i = blockIdx.x * blockDim.x + threadIdx.x;
    if (i < BB * NE) {
        g_ine[i] = 0.f; g_ei[i] = 0.f; g_ie[i] = 0.f; Iie[i] = 0.f;
        mem_e[i] = -65.0f; rc_e[i] = 0.f;
        mem_i[i] = -60.0f; rc_i[i] = 0.f;
        theta[i] = 20.0f; tp1[i] = 0.f; tp2[i] = 0.f;
    }
}

// Fused: W-reconstruct (clip(Wprev/d + sum_c part)) + gemm1 partials + W/rowsum emit.
// grid (7 e-tiles, 8 b-tiles, KC1 k-chunks), 256 thr, 64x64 tile, 4x4/thread.
// blockIdx.y==0 blocks also write Wout and rs[c][e] (chunk rowsums of new W).
__global__ __launch_bounds__(256) void k_g1(const float* __restrict__ x,
                                            const float* __restrict__ Wprev,
                                            const float* __restrict__ part,
                                            const float* __restrict__ dvec,
                                            float* __restrict__ Wout,
                                            float* __restrict__ rs,
                                            float* __restrict__ dgp, int t) {
    __shared__ float xs[16][68];   // [k][b_local]
    __shared__ float ws[16][68];   // [k][e_local]
    __shared__ float rsh[4][64];
    int lid = threadIdx.x;
    int tx = lid & 15, ty = lid >> 4;
    int e0 = blockIdx.x * 64, b0 = blockIdx.y * 64;
    int kbase = blockIdx.z * KCH1;
    int r = lid >> 2, cb = (lid & 3) * 4;   // staging: row r, k-offset cb
    int erow = e0 + r;
    bool ev = erow < NE;
    float dval = 1.0f;
    if (t > 0 && ev) dval = dvec[erow];

    float acc[4][4];
#pragma unroll
    for (int a = 0; a < 4; a++)
#pragma unroll
        for (int b = 0; b < 4; b++) acc[a][b] = 0.f;
    float rsacc = 0.f;

    float4 xv, wn;
    auto loadt = [&](int kt) {
        int k0 = kbase + kt * 16;
        xv = *(const float4*)&x[(b0 + r) * NIN + k0 + cb];
        if (ev) {
            float4 w = *(const float4*)&Wprev[erow * NIN + k0 + cb];
            if (t > 0) {
                int o = erow * NIN + k0 + cb;
                float4 s = make_float4(w.x / dval, w.y / dval, w.z / dval, w.w / dval);
#pragma unroll
                for (int c = 0; c < KC2; c++) {
                    float4 p = *(const float4*)&part[c * NE * NIN + o];
                    s.x += p.x; s.y += p.y; s.z += p.z; s.w += p.w;
                }
                w.x = fminf(fmaxf(s.x, 0.f), 1.f);
                w.y = fminf(fmaxf(s.y, 0.f), 1.f);
                w.z = fminf(fmaxf(s.z, 0.f), 1.f);
                w.w = fminf(fmaxf(s.w, 0.f), 1.f);
            }
            wn = w;
        } else {
            wn = make_float4(0.f, 0.f, 0.f, 0.f);
        }
    };

    loadt(0);
    for (int kt = 0; kt < KCH1 / 16; kt++) {
        // stage current regs -> LDS (transposed) + side effects
        xs[cb + 0][r] = xv.x; xs[cb + 1][r] = xv.y;
        xs[cb + 2][r] = xv.z; xs[cb + 3][r] = xv.w;
        ws[cb + 0][r] = wn.x; ws[cb + 1][r] = wn.y;
        ws[cb + 2][r] = wn.z; ws[cb + 3][r] = wn.w;
        if (blockIdx.y == 0 && ev) {
            *(float4*)&Wout[erow * NIN + kbase + kt * 16 + cb] = wn;
            rsacc += (wn.x + wn.y) + (wn.z + wn.w);
        }
        __syncthreads();
        if (kt < KCH1 / 16 - 1) loadt(kt + 1);   // prefetch next tile under FMAs
#pragma unroll
        for (int k = 0; k < 16; k++) {
            float4 av = *(const float4*)&xs[k][ty * 4];
            float4 bv = *(const float4*)&ws[k][tx * 4];
            float a[4] = {av.x, av.y, av.z, av.w};
            float b[4] = {bv.x, bv.y, bv.z, bv.w};
#pragma unroll
            for (int p = 0; p < 4; p++)
#pragma unroll
                for (int q = 0; q < 4; q++) acc[p][q] += a[p] * b[q];
        }
        __syncthreads();
    }

    if (blockIdx.y == 0) {
        rsh[lid & 3][r] = rsacc;
        __syncthreads();
        if (lid < 64 && e0 + lid < NE)
            rs[blockIdx.z * NE + e0 + lid] =
                (rsh[0][lid] + rsh[1][lid]) + (rsh[2][lid] + rsh[3][lid]);
    }

    if (e0 + tx * 4 < NE) {
        float* base = dgp + blockIdx.z * BB * NE;
#pragma unroll
        for (int p = 0; p < 4; p++) {
            float4 v = make_float4(acc[p][0], acc[p][1], acc[p][2], acc[p][3]);
            *(float4*)&base[(b0 + ty * 4 + p) * NE + e0 + tx * 4] = v;
        }
    }
}

// fused: blocks [0,512) = per-batch LIF phase (+ d[e] from rs); [512,708) = pre-trace
__global__ __launch_bounds__(512) void k_mid(const float* __restrict__ dgp,
                                             const float* __restrict__ rs,
                                             const float* __restrict__ xt,
                                             float* __restrict__ tr, int t,
                                             float* __restrict__ dvec,
                                             float* g_ine, float* g_ei, float* g_ie,
                                             float* Iie, float* mem_e, float* rc_e,
                                             float* mem_i, float* rc_i, float* theta,
                                             float* tp1, float* tp2,
                                             float* __restrict__ A1,
                                             float* __restrict__ A2,
                                             float* __restrict__ out_t) {
    if (blockIdx.x >= BB) {
        int base = (blockIdx.x - BB) * 2048 + threadIdx.x * 4;
        float4 xv = *(const float4*)&xt[base];
        float4 o;
        if (t == 0) {
            o = xv;
        } else {
            float4 tv = *(const float4*)&tr[base];
            o.x = (xv.x > 0.9f) ? 1.0f : tv.x * C_DECPRE;
            o.y = (xv.y > 0.9f) ? 1.0f : tv.y * C_DECPRE;
            o.z = (xv.z > 0.9f) ? 1.0f : tv.z * C_DECPRE;
            o.w = (xv.w > 0.9f) ? 1.0f : tv.w * C_DECPRE;
        }
        *(float4*)&tr[base] = o;
        return;
    }
    int b = blockIdx.x;
    int e = threadIdx.x;
    __shared__ float red[8];
    int idx = b * NE + e;

    float spk_i = 0.f, spk_e = 0.f;
    float g1 = 0.f, me = 0.f, re = 0.f, th = 0.f, g2 = 0.f, mi = 0.f, ri = 0.f;

    if (e < NE) {
        float dsum = 0.f;
#pragma unroll
        for (int c = 0; c < KC1; c++) dsum += rs[c * NE + e];
        float dv = dsum / 78.4f;
        if (b == 0) dvec[e] = dv;       // divisor for next step's W-reconstruct
        float dg = 0.f;
#pragma unroll
        for (int c = 0; c < KC1; c++) dg += dgp[c * BB * NE + idx];
        dg = dg / dv;
        g1 = g_ine[idx]; me = mem_e[idx]; re = rc_e[idx];
        th = theta[idx];
        float Ii = Iie[idx];
        float I_in = g1 * (0.0f - me);
        g1 = g1 + (dg - g1) * C_GSE;
        bool act = (re <= 0.0f);
        float I = I_in + Ii;
        if (act) me = me + ((-65.0f - me) + I) * C_KE;
        re = fmaxf(re - 0.5f, 0.0f);
        float thr = -72.0f + th;
        spk_e = (act && (me > thr)) ? 1.0f : 0.0f;
        if (spk_e > 0.0f) { me = -65.0f; re = 5.0f; }
        float dgei = spk_e * 10.4f;
        g2 = g_ei[idx]; mi = mem_i[idx]; ri = rc_i[idx];
        float I_ei = g2 * (0.0f - mi);
        g2 = g2 + (dgei - g2) * C_GSE;
        bool ai = (ri <= 0.0f);
        if (ai) mi = mi + ((-60.0f - mi) + I_ei) * C_KI;
        ri = fmaxf(ri - 0.5f, 0.0f);
        spk_i = (ai && (mi > -40.0f)) ? 1.0f : 0.0f;
        if (spk_i > 0.0f) { mi = -45.0f; ri = 2.0f; }
    }
    // spike-count sum over e: integer-valued -> exact in any order
    float v = spk_i;
#pragma unroll
    for (int o = 32; o > 0; o >>= 1) v += __shfl_down(v, o, 64);
    if ((e & 63) == 0) red[e >> 6] = v;
    __syncthreads();
    float S = ((red[0] + red[1]) + (red[2] + red[3])) +
              ((red[4] + red[5]) + (red[6] + red[7]));
    if (e < NE) {
        float dgie = 17.0f * (S - spk_i);
        float g3 = g_ie[idx];
        float Iie_new = g3 * (-100.0f - me);
        g3 = g3 + (dgie - g3) * C_GSI;
        th = th * C_DECTH + 0.05f * spk_e;
        float r1 = tp1[idx] * C_DEC1;
        float r2 = tp2[idx] * C_DEC2;
        bool fired = spk_e > 0.9f;
        A1[idx] = r1;
        A2[idx] = spk_e * r2;
        tp1[idx] = fired ? 1.0f : r1;
        tp2[idx] = fired ? 1.0f : r2;
        g_ine[idx] = g1; g_ei[idx] = g2; g_ie[idx] = g3; Iie[idx] = Iie_new;
        mem_e[idx] = me; rc_e[idx] = re; mem_i[idx] = mi; rc_i[idx] = ri;
        theta[idx] = th;
        out_t[idx] = spk_e;
    }
}

// gemm2 partials: part[c][e][i] = NU_PRE*sum_b A1[b,e]*x[b,i] + NU_POST*sum_b A2[b,e]*tr[b,i]
__global__ __launch_bounds__(256) void k_gemm2(const float* __restrict__ A1,
                                               const float* __restrict__ A2,
                                               const float* __restrict__ xt,
                                               const float* __restrict__ tr,
                                               float* __restrict__ part) {
    __shared__ float a1s[16][68];
    __shared__ float a2s[16][68];
    __shared__ float xs[16][68];
    __shared__ float ts[16][68];
    int tx = threadIdx.x & 15, ty = threadIdx.x >> 4;
    int lid = threadIdx.x;
    int i0 = blockIdx.x * 64, e0 = blockIdx.y * 64;
    int bbase = blockIdx.z * KCH2;
    int r = lid >> 4, cb = (lid & 15) * 4;

    float s1[4][4], s2[4][4];
#pragma unroll
    for (int a = 0; a < 4; a++)
#pragma unroll
        for (int b = 0; b < 4; b++) { s1[a][b] = 0.f; s2[a][b] = 0.f; }

    float4 v1, v2, xv, tv;
    auto loadt = [&](int bt) {
        int b0 = bbase + bt * 16;
        if (e0 + cb < NE) {
            v1 = *(const float4*)&A1[(b0 + r) * NE + e0 + cb];
            v2 = *(const float4*)&A2[(b0 + r) * NE + e0 + cb];
        } else {
            v1 = make_float4(0.f, 0.f, 0.f, 0.f);
            v2 = v1;
        }
        if (i0 + cb < NIN) {
            xv = *(const float4*)&xt[(b0 + r) * NIN + i0 + cb];
            tv = *(const float4*)&tr[(b0 + r) * NIN + i0 + cb];
        } else {
            xv = make_float4(0.f, 0.f, 0.f, 0.f);
            tv = xv;
        }
    };

    loadt(0);
    for (int bt = 0; bt < KCH2 / 16; bt++) {
        *(float4*)&a1s[r][cb] = v1;
        *(float4*)&a2s[r][cb] = v2;
        *(float4*)&xs[r][cb] = xv;
        *(float4*)&ts[r][cb] = tv;
        __syncthreads();
        if (bt < KCH2 / 16 - 1) loadt(bt + 1);   // prefetch under FMAs
#pragma unroll
        for (int k = 0; k < 16; k++) {
            float4 a1v = *(const float4*)&a1s[k][ty * 4];
            float4 a2v = *(const float4*)&a2s[k][ty * 4];
            float4 xvv = *(const float4*)&xs[k][tx * 4];
            float4 tvv = *(const float4*)&ts[k][tx * 4];
            float a1[4] = {a1v.x, a1v.y, a1v.z, a1v.w};
            float a2[4] = {a2v.x, a2v.y, a2v.z, a2v.w};
            float xx[4] = {xvv.x, xvv.y, xvv.z, xvv.w};
            float tt[4] = {tvv.x, tvv.y, tvv.z, tvv.w};
#pragma unroll
            for (int p = 0; p < 4; p++)
#pragma unroll
                for (int q = 0; q < 4; q++) {
                    s1[p][q] += a1[p] * xx[q];
                    s2[p][q] += a2[p] * tt[q];
                }
        }
        __syncthreads();
    }
    if (e0 + ty * 4 < NE && i0 + tx * 4 < NIN) {
        float* base = part + blockIdx.z * NE * NIN;
#pragma unroll
        for (int p = 0; p < 4; p++) {
            float4 v = make_float4(C_NUPRE * s1[p][0] + C_NUPOST * s2[p][0],
                                   C_NUPRE * s1[p][1] + C_NUPOST * s2[p][1],
                                   C_NUPRE * s1[p][2] + C_NUPOST * s2[p][2],
                                   C_NUPRE * s1[p][3] + C_NUPOST * s2[p][3]);
            *(float4*)&base[(e0 + ty * 4 + p) * NIN + i0 + tx * 4] = v;
        }
    }
}

extern "C" void kernel_launch(void* const* d_in, const int* in_sizes, int n_in,
                              void* d_out, int out_size, void* d_ws, size_t ws_size,
                              hipStream_t stream) {
    const float* x     = (const float*)d_in[0];  // (50, 512, 784)
    const float* W_ine = (const float*)d_in[1];  // (400, 784)

    float* p = (float*)d_ws;
    float* wbuf0 = p; p += NE * NIN;
    float* wbuf1 = p; p += NE * NIN;
    float* rs    = p; p += KC1 * NE;
    float* dbuf  = p; p += NE;
    float* dgp   = p; p += KC1 * BB * NE;
    float* part  = p; p += KC2 * NE * NIN;
    float* A1    = p; p += BB * NE;
    float* A2    = p; p += BB * NE;
    float* g_ine = p; p += BB * NE;
    float* g_ei  = p; p += BB * NE;
    float* g_ie  = p; p += BB * NE;
    float* Iie   = p; p += BB * NE;
    float* mem_e = p; p += BB * NE;
    float* rc_e  = p; p += BB * NE;
    float* mem_i = p; p += BB * NE;
    float* rc_i  = p; p += BB * NE;
    float* theta = p; p += BB * NE;
    float* tp1   = p; p += BB * NE;
    float* tp2   = p; p += BB * NE;
    float* tr    = p; p += BB * NIN;

    k_init<<<(BB * NE + 255) / 256, 256, 0, stream>>>(g_ine, g_ei, g_ie, Iie, mem_e,
                                                      rc_e, mem_i, rc_i, theta, tp1, tp2);

    for (int t = 0; t < TT; t++) {
        const float* xt = x + (size_t)t * BB * NIN;
        float* out_t = (float*)d_out + (size_t)t * BB * NE;
        const float* Wprev = (t == 0) ? W_ine : ((t & 1) ? wbuf0 : wbuf1);
        float* Wout = (t & 1) ? wbuf1 : wbuf0;
        k_g1<<<dim3(7, 8, KC1), 256, 0, stream>>>(xt, Wprev, part, dbuf, Wout, rs, dgp, t);
        k_mid<<<BB + 196, 512, 0, stream>>>(dgp, rs, xt, tr, t, dbuf, g_ine, g_ei, g_ie,
                                            Iie, mem_e, rc_e, mem_i, rc_i, theta,
                                            tp1, tp2, A1, A2, out_t);
        if (t < TT - 1)
            k_gemm2<<<dim3(13, 7, KC2), 256, 0, stream>>>(A1, A2, xt, tr, part);
    }
}